// Round 10
// baseline (443.770 us; speedup 1.0000x reference)
//
#include <hip/hip_runtime.h>
#include <math.h>

#define EPS_BN 1e-5f
#define CAP 48          // fixed CSR capacity per node; P(Poisson(10) >= 48) ~ 2e-17
#define APL_NODES 64    // pool tile
#define RCMAX 8         // max graph-ids per pool tile on the LDS fast path

// ---------------------------------------------------------------------------
// fixed-cap CSR pull, NO sentinel init (R8-proven): full quads via int4;
// tail quad index-clamped (garbage slots -> index i, weight 0).
// ---------------------------------------------------------------------------
__device__ __forceinline__ float4 pull_fixed(const float4* __restrict__ h4, const int* __restrict__ icnt,
                                             const int* __restrict__ csr, int i, int q) {
    int degt = icnt[i];
    float di = rsqrtf((float)(degt + 1));
    float4 acc = h4[i * 16 + q];
    float dd = di * di;
    acc.x *= dd; acc.y *= dd; acc.z *= dd; acc.w *= dd;
    int deg = min(degt, CAP);
    int base = i * CAP;
    int k4 = deg & ~3;
    for (int k = 0; k < k4; k += 4) {
        int4 rr = *(const int4*)(csr + base + k);   // 16B aligned
        float w0 = rsqrtf((float)(icnt[rr.x] + 1)) * di;
        float w1 = rsqrtf((float)(icnt[rr.y] + 1)) * di;
        float w2 = rsqrtf((float)(icnt[rr.z] + 1)) * di;
        float w3 = rsqrtf((float)(icnt[rr.w] + 1)) * di;
        float4 v0 = h4[rr.x * 16 + q];
        float4 v1 = h4[rr.y * 16 + q];
        float4 v2 = h4[rr.z * 16 + q];
        float4 v3 = h4[rr.w * 16 + q];
        acc.x += v0.x * w0 + v1.x * w1 + v2.x * w2 + v3.x * w3;
        acc.y += v0.y * w0 + v1.y * w1 + v2.y * w2 + v3.y * w3;
        acc.z += v0.z * w0 + v1.z * w1 + v2.z * w2 + v3.z * w3;
        acc.w += v0.w * w0 + v1.w * w1 + v2.w * w2 + v3.w * w3;
    }
    if (k4 < deg) {
        int rem = deg - k4;                         // 1..3
        int4 rr = *(const int4*)(csr + base + k4);  // in-bounds; tail slots may be garbage
        int r0 = rr.x;                              // rem >= 1: valid
        int r1 = (rem > 1) ? rr.y : i;              // clamp garbage index BEFORE gather
        int r2 = (rem > 2) ? rr.z : i;
        float w0 = rsqrtf((float)(icnt[r0] + 1)) * di;
        float w1 = (rem > 1) ? rsqrtf((float)(icnt[r1] + 1)) * di : 0.0f;
        float w2 = (rem > 2) ? rsqrtf((float)(icnt[r2] + 1)) * di : 0.0f;
        float4 v0 = h4[r0 * 16 + q];
        float4 v1 = h4[r1 * 16 + q];
        float4 v2 = h4[r2 * 16 + q];
        acc.x += v0.x * w0 + v1.x * w1 + v2.x * w2;
        acc.y += v0.y * w0 + v1.y * w1 + v2.y * w2;
        acc.z += v0.z * w0 + v1.z * w1 + v2.z * w2;
        acc.w += v0.w * w0 + v1.w * w1 + v2.w * w2;
    }
    return acc;
}

// ---------------------------------------------------------------------------
// shared GEMM tile: out[tile*256 .. +255][64] = act(in) @ W^T, W in LDS
// ---------------------------------------------------------------------------
template <bool ACT>
__device__ __forceinline__ void gemm_tile(const float4* __restrict__ in4, const float4* Wl,
                                          const float4* scl, const float4* shl,
                                          float4* __restrict__ out4, int n, int tile, int tid) {
    int hg = tid >> 6;          // wave-uniform h-group
    int h0 = hg * 16;
    int ng = tid & 63;
    int n0 = tile * 256 + 4 * ng;
    float acc[4][16];
#pragma unroll
    for (int j = 0; j < 4; ++j)
#pragma unroll
        for (int k = 0; k < 16; ++k) acc[j][k] = 0.0f;
    bool valid[4];
#pragma unroll
    for (int j = 0; j < 4; ++j) valid[j] = (n0 + j) < n;
    for (int f4 = 0; f4 < 16; ++f4) {
        float4 sc, sh;
        if (ACT) { sc = scl[f4]; sh = shl[f4]; }
        float4 xv[4];
#pragma unroll
        for (int j = 0; j < 4; ++j) {
            float4 v = valid[j] ? in4[(n0 + j) * 16 + f4] : float4{0.f, 0.f, 0.f, 0.f};
            if (ACT) {
                v.x = fmaxf(v.x * sc.x + sh.x, 0.0f);
                v.y = fmaxf(v.y * sc.y + sh.y, 0.0f);
                v.z = fmaxf(v.z * sc.z + sh.z, 0.0f);
                v.w = fmaxf(v.w * sc.w + sh.w, 0.0f);
            }
            xv[j] = v;
        }
#pragma unroll
        for (int hh = 0; hh < 16; ++hh) {
            float4 w = Wl[(h0 + hh) * 16 + f4];
#pragma unroll
            for (int j = 0; j < 4; ++j) {
                acc[j][hh] += xv[j].x * w.x;
                acc[j][hh] += xv[j].y * w.y;
                acc[j][hh] += xv[j].z * w.z;
                acc[j][hh] += xv[j].w * w.w;
            }
        }
    }
#pragma unroll
    for (int j = 0; j < 4; ++j) {
        if (!valid[j]) continue;
#pragma unroll
        for (int q = 0; q < 4; ++q) {
            float4 o = {acc[j][4 * q], acc[j][4 * q + 1], acc[j][4 * q + 2], acc[j][4 * q + 3]};
            out4[(n0 + j) * 16 + (h0 >> 2) + q] = o;
        }
    }
}

// ===========================================================================
// 1. init (tiny): zero icnt/gsum/gcnt/done + BN param folding. No csr init.
// ===========================================================================
__global__ __launch_bounds__(256) void k_init(int* icnt, float* gsum, float* gcnt, int* done, int n,
    const float* b1, const float* g1, const float* bb1, const float* m1, const float* v1,
    const float* b2, const float* g2, const float* bb2, const float* m2, const float* v2,
    float* sc1, float* sh1, float* sc2, float* sh2) {
    int i = blockIdx.x * 256 + threadIdx.x;
    if (i <= n) icnt[i] = 0;
    if (i < 4096) gsum[i] = 0.0f;
    if (i < 64) gcnt[i] = 0.0f;
    if (i == 0) *done = 0;
    if (blockIdx.x == 0 && threadIdx.x < 64) {
        int t = threadIdx.x;
        float s1 = g1[t] / sqrtf(v1[t] + EPS_BN);
        sc1[t] = s1;
        sh1[t] = (b1[t] - m1[t]) * s1 + bb1[t];
        float s2 = g2[t] / sqrtf(v2[t] + EPS_BN);
        sc2[t] = s2;
        sh2[t] = (b2[t] - m2[t]) * s2 + bb2[t];
    }
}

// ===========================================================================
// 2. blocks [0,nbg): GEMM1 x@W1^T -> bufA.  blocks [nbg,..): fixed-cap fill.
// ===========================================================================
__global__ __launch_bounds__(256) void k_fillgemm_f(int nbg,
    const float* __restrict__ in, const float* __restrict__ W, float* __restrict__ out, int n,
    const int* __restrict__ row, const int* __restrict__ col, int* icnt, int* csr, int e) {
    __shared__ float4 Wl[1024];
    if ((int)blockIdx.x < nbg) {
        const float4* W4 = (const float4*)W;
        for (int i = threadIdx.x; i < 1024; i += 256) Wl[i] = W4[i];
        __syncthreads();
        gemm_tile<false>((const float4*)in, Wl, nullptr, nullptr, (float4*)out, n, blockIdx.x, threadIdx.x);
    } else {
        int i0 = ((blockIdx.x - nbg) * 256 + threadIdx.x) * 4;
        if (i0 + 3 < e) {
            int r0 = row[i0], r1 = row[i0 + 1], r2 = row[i0 + 2], r3 = row[i0 + 3];
            int c0 = col[i0], c1 = col[i0 + 1], c2 = col[i0 + 2], c3 = col[i0 + 3];
            int u0 = atomicAdd(&icnt[c0], 1);
            int u1 = atomicAdd(&icnt[c1], 1);
            int u2 = atomicAdd(&icnt[c2], 1);
            int u3 = atomicAdd(&icnt[c3], 1);
            if (u0 < CAP) csr[c0 * CAP + u0] = r0;
            if (u1 < CAP) csr[c1 * CAP + u1] = r1;
            if (u2 < CAP) csr[c2 * CAP + u2] = r2;
            if (u3 < CAP) csr[c3 * CAP + u3] = r3;
        } else {
            for (int i = i0; i < e; ++i) {
                int c = col[i];
                int u = atomicAdd(&icnt[c], 1);
                if (u < CAP) csr[c * CAP + u] = row[i];
            }
        }
    }
}

// ===========================================================================
// 3. apply1: bufB = A_hat @ bufA
// ===========================================================================
__global__ __launch_bounds__(256) void k_apply_f(const float* __restrict__ h, const int* __restrict__ icnt,
                                                 const int* __restrict__ csr, float* __restrict__ out, int n) {
    int gid = blockIdx.x * 256 + threadIdx.x;
    int i = gid >> 4, q = gid & 15;
    if (i >= n) return;
    float4 acc = pull_fixed((const float4*)h, icnt, csr, i, q);
    ((float4*)out)[i * 16 + q] = acc;
}

// ===========================================================================
// 4. gemm2: bufA = relu(sc1*bufB+sh1) @ W2^T   (act1 folded into input read)
// ===========================================================================
__global__ __launch_bounds__(256) void k_gemm2(const float* __restrict__ in, const float* __restrict__ W,
                                               const float* __restrict__ scale, const float* __restrict__ shift,
                                               float* __restrict__ out, int n) {
    __shared__ float4 Wl[1056];
    const float4* W4 = (const float4*)W;
    for (int i = threadIdx.x; i < 1024; i += 256) Wl[i] = W4[i];
    if (threadIdx.x < 16) {
        Wl[1024 + threadIdx.x] = ((const float4*)scale)[threadIdx.x];
        Wl[1040 + threadIdx.x] = ((const float4*)shift)[threadIdx.x];
    }
    __syncthreads();
    gemm_tile<true>((const float4*)in, Wl, Wl + 1024, Wl + 1040, (float4*)out, n, blockIdx.x, threadIdx.x);
}

// ===========================================================================
// 5. applypool + (last block) spill-free MLP head
// ===========================================================================
union PoolS {
    struct { float spart[RCMAX * 64]; float scnt[RCMAX]; } pool;   // ~2.3 KB
    struct { float pooled[4096]; float opart[4][64]; } mlp;        // ~17.4 KB
};

__global__ __launch_bounds__(256) void k_applypoolmlp(
    const float* __restrict__ h, const int* __restrict__ icnt, const int* __restrict__ csr,
    const int* __restrict__ batch,
    const float* __restrict__ sc, const float* __restrict__ sh,
    float* gsum, float* gcnt, int* done, int n,
    const float* __restrict__ l1W, const float* __restrict__ l1b,
    const float* __restrict__ l2W, const float* __restrict__ l2b,
    float* __restrict__ outp) {
    __shared__ PoolS s;
    __shared__ int last_flag;
    int node0 = blockIdx.x * APL_NODES;     // grid is exact: node0 < n always
    int last = min(node0 + APL_NODES - 1, n - 1);
    int g0 = batch[node0];
    int rc = batch[last] - g0 + 1;          // contiguous (batch sorted)
    bool lds_path = (rc <= RCMAX);
    if (lds_path) {
        for (int idx = threadIdx.x; idx < rc * 64; idx += 256) s.pool.spart[idx] = 0.0f;
        if (threadIdx.x < rc) s.pool.scnt[threadIdx.x] = 0.0f;
    }
    __syncthreads();

    int q = threadIdx.x & 15;
    float4 s4 = ((const float4*)sc)[q];
    float4 b4 = ((const float4*)sh)[q];

    for (int it = 0; it < APL_NODES / 16; ++it) {   // 4 iterations
        int i = node0 + it * 16 + (threadIdx.x >> 4);
        if (i < n) {
            float4 acc = pull_fixed((const float4*)h, icnt, csr, i, q);
            acc.x = fmaxf(acc.x * s4.x + b4.x, 0.0f);
            acc.y = fmaxf(acc.y * s4.y + b4.y, 0.0f);
            acc.z = fmaxf(acc.z * s4.z + b4.z, 0.0f);
            acc.w = fmaxf(acc.w * s4.w + b4.w, 0.0f);
            if (lds_path) {
                int gl = batch[i] - g0;
                float* pp = &s.pool.spart[gl * 64 + q * 4];
                atomicAdd(pp + 0, acc.x);
                atomicAdd(pp + 1, acc.y);
                atomicAdd(pp + 2, acc.z);
                atomicAdd(pp + 3, acc.w);
                if (q == 0) atomicAdd(&s.pool.scnt[gl], 1.0f);
            } else {
                int gg = batch[i];
                float* pp = &gsum[gg * 64 + q * 4];
                atomicAdd(pp + 0, acc.x);
                atomicAdd(pp + 1, acc.y);
                atomicAdd(pp + 2, acc.z);
                atomicAdd(pp + 3, acc.w);
                if (q == 0) atomicAdd(&gcnt[gg], 1.0f);
            }
        }
    }
    __syncthreads();
    if (lds_path) {
        for (int idx = threadIdx.x; idx < rc * 64; idx += 256) {
            int gl = idx >> 6, f = idx & 63;
            atomicAdd(&gsum[(g0 + gl) * 64 + f], s.pool.spart[idx]);
        }
        if (threadIdx.x < rc) atomicAdd(&gcnt[g0 + threadIdx.x], s.pool.scnt[threadIdx.x]);
    }

    // ---- done-counter: last block runs the MLP head (spill-free) ----
    __syncthreads();
    if (threadIdx.x == 0) {
        __threadfence();  // make this block's gsum/gcnt atomics device-visible
        int old = __hip_atomic_fetch_add(done, 1, __ATOMIC_ACQ_REL, __HIP_MEMORY_SCOPE_AGENT);
        last_flag = (old == (int)gridDim.x - 1) ? 1 : 0;
    }
    __syncthreads();
    if (!last_flag) return;

    // stage pooled means into LDS (16 entries per thread -> no reg pressure)
    for (int idx = threadIdx.x; idx < 4096; idx += 256) {
        int g = idx >> 6;
        float cnt = __hip_atomic_load(&gcnt[g], __ATOMIC_RELAXED, __HIP_MEMORY_SCOPE_AGENT);
        float v = __hip_atomic_load(&gsum[idx], __ATOMIC_RELAXED, __HIP_MEMORY_SCOPE_AGENT);
        s.mlp.pooled[idx] = v / fmaxf(cnt, 1.0f);
    }
    __syncthreads();

    // thread = (part 0..3, g 0..63): part handles hidden units [part*8, +8)
    {
        int g = threadIdx.x & 63;
        int part = threadIdx.x >> 6;
        const float* pv = &s.mlp.pooled[g * 64];
        float o = 0.0f;
        for (int j = part * 8; j < part * 8 + 8; ++j) {
            float a = l1b[j];
            const float* wrow = &l1W[j * 64];
#pragma unroll
            for (int hh = 0; hh < 64; ++hh) a += pv[hh] * wrow[hh];
            o += fmaxf(a, 0.0f) * l2W[j];
        }
        s.mlp.opart[part][g] = o;
    }
    __syncthreads();
    if (threadIdx.x < 64) {
        int g = threadIdx.x;
        outp[g] = l2b[0] + s.mlp.opart[0][g] + s.mlp.opart[1][g]
                         + s.mlp.opart[2][g] + s.mlp.opart[3][g];
    }
}

// ---------------------------------------------------------------------------
extern "C" void kernel_launch(void* const* d_in, const int* in_sizes, int n_in,
                              void* d_out, int out_size, void* d_ws, size_t ws_size,
                              hipStream_t stream) {
    const int N = in_sizes[0] / 64;  // 100000
    const int E = in_sizes[1] / 2;   // 1000000

    const float* x    = (const float*)d_in[0];
    const int*  row   = (const int*)d_in[1];
    const int*  colp  = ((const int*)d_in[1]) + E;
    const int*  batch = (const int*)d_in[2];
    const float* W1   = (const float*)d_in[3];
    const float* b1   = (const float*)d_in[4];
    const float* W2   = (const float*)d_in[5];
    const float* b2   = (const float*)d_in[6];
    const float* bn1g = (const float*)d_in[7];
    const float* bn1b = (const float*)d_in[8];
    const float* bn1m = (const float*)d_in[9];
    const float* bn1v = (const float*)d_in[10];
    const float* bn2g = (const float*)d_in[11];
    const float* bn2b = (const float*)d_in[12];
    const float* bn2m = (const float*)d_in[13];
    const float* bn2v = (const float*)d_in[14];
    const float* l1W  = (const float*)d_in[15];
    const float* l1b  = (const float*)d_in[16];
    const float* l2W  = (const float*)d_in[17];
    const float* l2b  = (const float*)d_in[18];
    float* out = (float*)d_out;

    // workspace layout (element offsets multiples of 4 -> 16B aligned)
    int* icnt = (int*)d_ws;                          // N+4 (icnt[N]=0 used by clamp path)
    float* sc1 = (float*)(icnt + N + 4);
    float* sh1 = sc1 + 64;
    float* sc2 = sh1 + 64;
    float* sh2 = sc2 + 64;
    float* gsum = sh2 + 64;                          // 4096
    float* gcnt = gsum + 4096;                       // 64
    int* done = (int*)(gcnt + 64);                   // 4
    int* csr = done + 4;                             // N*CAP
    float* bufA = (float*)(csr + (size_t)N * CAP);   // N*64
    float* bufB = bufA + (size_t)N * 64;             // N*64

    int nb_n   = (N + 255) / 256;
    int nb_e4  = ((E + 3) / 4 + 255) / 256;
    int nb_n16 = (N * 16 + 255) / 256;
    int nb_apl = (N + APL_NODES - 1) / APL_NODES;

    k_init<<<nb_n, 256, 0, stream>>>(icnt, gsum, gcnt, done, N,
                                     b1, bn1g, bn1b, bn1m, bn1v,
                                     b2, bn2g, bn2b, bn2m, bn2v,
                                     sc1, sh1, sc2, sh2);
    k_fillgemm_f<<<nb_n + nb_e4, 256, 0, stream>>>(nb_n, x, W1, bufA, N,
                                                   row, colp, icnt, csr, E);
    k_apply_f<<<nb_n16, 256, 0, stream>>>(bufA, icnt, csr, bufB, N);
    k_gemm2<<<nb_n, 256, 0, stream>>>(bufB, W2, sc1, sh1, bufA, N);
    k_applypoolmlp<<<nb_apl, 256, 0, stream>>>(bufA, icnt, csr, batch, sc2, sh2,
                                               gsum, gcnt, done, N,
                                               l1W, l1b, l2W, l2b, out);
}

// Round 11
// 347.872 us; speedup vs baseline: 1.2757x; 1.2757x over previous
//
#include <hip/hip_runtime.h>
#include <math.h>

#define EPS_BN 1e-5f
#define CAP 48          // fixed CSR capacity per node; P(Poisson(10) >= 48) ~ 2e-17

// ---------------------------------------------------------------------------
// weighted fixed-cap CSR pull (R7-proven sentinel form): pad slots hold index
// n, icnt[n]=0 and h row n is zeroed, so pads contribute exactly 0.
// Used for layer 1 (input rows are unscaled h1).
// ---------------------------------------------------------------------------
__device__ __forceinline__ float4 pull_fixed(const float4* __restrict__ h4, const int* __restrict__ icnt,
                                             const int* __restrict__ csr, int i, int q) {
    int deg = icnt[i];
    float di = rsqrtf((float)(deg + 1));
    float4 acc = h4[i * 16 + q];
    float dd = di * di;
    acc.x *= dd; acc.y *= dd; acc.z *= dd; acc.w *= dd;
    int degc = min(deg, CAP);
    int base = i * CAP;
    int kend = base + ((degc + 3) & ~3);
    for (int k = base; k < kend; k += 4) {
        int4 rr = *(const int4*)(csr + k);          // 16B aligned (CAP mult of 4)
        float w0 = rsqrtf((float)(icnt[rr.x] + 1)) * di;
        float w1 = rsqrtf((float)(icnt[rr.y] + 1)) * di;
        float w2 = rsqrtf((float)(icnt[rr.z] + 1)) * di;
        float w3 = rsqrtf((float)(icnt[rr.w] + 1)) * di;
        float4 v0 = h4[rr.x * 16 + q];
        float4 v1 = h4[rr.y * 16 + q];
        float4 v2 = h4[rr.z * 16 + q];
        float4 v3 = h4[rr.w * 16 + q];
        acc.x += v0.x * w0 + v1.x * w1 + v2.x * w2 + v3.x * w3;
        acc.y += v0.y * w0 + v1.y * w1 + v2.y * w2 + v3.y * w3;
        acc.z += v0.z * w0 + v1.z * w1 + v2.z * w2 + v3.z * w3;
        acc.w += v0.w * w0 + v1.w * w1 + v2.w * w2 + v3.w * w3;
    }
    return acc;
}

// ---------------------------------------------------------------------------
// UNWEIGHTED pull for layer 2: input rows are pre-scaled g2[j] = dinv[j]*h2[j]
// (done in gemm2's epilogue).  c2[i] = dinv[i] * (g2[i] + sum g2[r]).
// 5 memory ops per quad instead of 8 — no per-edge icnt gathers / rsqrt.
// ---------------------------------------------------------------------------
__device__ __forceinline__ float4 pull_plain(const float4* __restrict__ h4, const int* __restrict__ icnt,
                                             const int* __restrict__ csr, int i, int q) {
    int deg = icnt[i];
    float4 acc = h4[i * 16 + q];                    // g2[i]
    int degc = min(deg, CAP);
    int base = i * CAP;
    int kend = base + ((degc + 3) & ~3);
    for (int k = base; k < kend; k += 4) {
        int4 rr = *(const int4*)(csr + k);          // pads -> row n (zeroed)
        float4 v0 = h4[rr.x * 16 + q];
        float4 v1 = h4[rr.y * 16 + q];
        float4 v2 = h4[rr.z * 16 + q];
        float4 v3 = h4[rr.w * 16 + q];
        acc.x += v0.x + v1.x + v2.x + v3.x;
        acc.y += v0.y + v1.y + v2.y + v3.y;
        acc.z += v0.z + v1.z + v2.z + v3.z;
        acc.w += v0.w + v1.w + v2.w + v3.w;
    }
    float di = rsqrtf((float)(deg + 1));
    acc.x *= di; acc.y *= di; acc.z *= di; acc.w *= di;
    return acc;
}

// ---------------------------------------------------------------------------
// shared GEMM tile: out[tile*256 .. +255][64] = act(in) @ W^T, W in LDS
// ---------------------------------------------------------------------------
template <bool ACT>
__device__ __forceinline__ void gemm_tile(const float4* __restrict__ in4, const float4* Wl,
                                          const float4* scl, const float4* shl,
                                          float4* __restrict__ out4, int n, int tile, int tid) {
    int hg = tid >> 6;          // wave-uniform h-group
    int h0 = hg * 16;
    int ng = tid & 63;
    int n0 = tile * 256 + 4 * ng;
    float acc[4][16];
#pragma unroll
    for (int j = 0; j < 4; ++j)
#pragma unroll
        for (int k = 0; k < 16; ++k) acc[j][k] = 0.0f;
    bool valid[4];
#pragma unroll
    for (int j = 0; j < 4; ++j) valid[j] = (n0 + j) < n;
    for (int f4 = 0; f4 < 16; ++f4) {
        float4 sc, sh;
        if (ACT) { sc = scl[f4]; sh = shl[f4]; }
        float4 xv[4];
#pragma unroll
        for (int j = 0; j < 4; ++j) {
            float4 v = valid[j] ? in4[(n0 + j) * 16 + f4] : float4{0.f, 0.f, 0.f, 0.f};
            if (ACT) {
                v.x = fmaxf(v.x * sc.x + sh.x, 0.0f);
                v.y = fmaxf(v.y * sc.y + sh.y, 0.0f);
                v.z = fmaxf(v.z * sc.z + sh.z, 0.0f);
                v.w = fmaxf(v.w * sc.w + sh.w, 0.0f);
            }
            xv[j] = v;
        }
#pragma unroll
        for (int hh = 0; hh < 16; ++hh) {
            float4 w = Wl[(h0 + hh) * 16 + f4];
#pragma unroll
            for (int j = 0; j < 4; ++j) {
                acc[j][hh] += xv[j].x * w.x;
                acc[j][hh] += xv[j].y * w.y;
                acc[j][hh] += xv[j].z * w.z;
                acc[j][hh] += xv[j].w * w.w;
            }
        }
    }
#pragma unroll
    for (int j = 0; j < 4; ++j) {
        if (!valid[j]) continue;
#pragma unroll
        for (int q = 0; q < 4; ++q) {
            float4 o = {acc[j][4 * q], acc[j][4 * q + 1], acc[j][4 * q + 2], acc[j][4 * q + 3]};
            out4[(n0 + j) * 16 + (h0 >> 2) + q] = o;
        }
    }
}

// ===========================================================================
// 1. init: sentinel csr fill, zero icnt/gsum/gcnt/sentinel-rows, BN params
// ===========================================================================
__global__ __launch_bounds__(256) void k_init_f(int* icnt, int* csr, float* gsum, float* gcnt,
    float* rowA, float* rowB, int n,
    const float* b1, const float* g1, const float* bb1, const float* m1, const float* v1,
    const float* b2, const float* g2, const float* bb2, const float* m2, const float* v2,
    float* sc1, float* sh1, float* sc2, float* sh2) {
    int gtid = blockIdx.x * 256 + threadIdx.x;
    int total4 = n * (CAP / 4);
    if (gtid < total4) ((int4*)csr)[gtid] = int4{n, n, n, n};   // sentinel
    if (gtid <= n) icnt[gtid] = 0;                              // incl icnt[n]=0
    if (gtid < 4096) gsum[gtid] = 0.0f;
    if (gtid < 64) { gcnt[gtid] = 0.0f; rowA[gtid] = 0.0f; rowB[gtid] = 0.0f; }
    if (blockIdx.x == 0 && threadIdx.x < 64) {
        int t = threadIdx.x;
        float s1 = g1[t] / sqrtf(v1[t] + EPS_BN);
        sc1[t] = s1;
        sh1[t] = (b1[t] - m1[t]) * s1 + bb1[t];
        float s2 = g2[t] / sqrtf(v2[t] + EPS_BN);
        sc2[t] = s2;
        sh2[t] = (b2[t] - m2[t]) * s2 + bb2[t];
    }
}

// ===========================================================================
// 2. blocks [0,nbg): GEMM1 x@W1^T -> bufA.  blocks [nbg,..): fixed-cap fill.
// ===========================================================================
__global__ __launch_bounds__(256) void k_fillgemm_f(int nbg,
    const float* __restrict__ in, const float* __restrict__ W, float* __restrict__ out, int n,
    const int* __restrict__ row, const int* __restrict__ col, int* icnt, int* csr, int e) {
    __shared__ float4 Wl[1024];
    if ((int)blockIdx.x < nbg) {
        const float4* W4 = (const float4*)W;
        for (int i = threadIdx.x; i < 1024; i += 256) Wl[i] = W4[i];
        __syncthreads();
        gemm_tile<false>((const float4*)in, Wl, nullptr, nullptr, (float4*)out, n, blockIdx.x, threadIdx.x);
    } else {
        int i0 = ((blockIdx.x - nbg) * 256 + threadIdx.x) * 4;
        if (i0 + 3 < e) {
            int r0 = row[i0], r1 = row[i0 + 1], r2 = row[i0 + 2], r3 = row[i0 + 3];
            int c0 = col[i0], c1 = col[i0 + 1], c2 = col[i0 + 2], c3 = col[i0 + 3];
            int u0 = atomicAdd(&icnt[c0], 1);
            int u1 = atomicAdd(&icnt[c1], 1);
            int u2 = atomicAdd(&icnt[c2], 1);
            int u3 = atomicAdd(&icnt[c3], 1);
            if (u0 < CAP) csr[c0 * CAP + u0] = r0;
            if (u1 < CAP) csr[c1 * CAP + u1] = r1;
            if (u2 < CAP) csr[c2 * CAP + u2] = r2;
            if (u3 < CAP) csr[c3 * CAP + u3] = r3;
        } else {
            for (int i = i0; i < e; ++i) {
                int c = col[i];
                int u = atomicAdd(&icnt[c], 1);
                if (u < CAP) csr[c * CAP + u] = row[i];
            }
        }
    }
}

// ===========================================================================
// 3. apply1: bufB = A_hat @ bufA  (weighted pull; bufA rows are unscaled h1)
// ===========================================================================
__global__ __launch_bounds__(256) void k_apply_f(const float* __restrict__ h, const int* __restrict__ icnt,
                                                 const int* __restrict__ csr, float* __restrict__ out, int n) {
    int gid = blockIdx.x * 256 + threadIdx.x;
    int i = gid >> 4, q = gid & 15;
    if (i >= n) return;
    float4 acc = pull_fixed((const float4*)h, icnt, csr, i, q);
    ((float4*)out)[i * 16 + q] = acc;
}

// ===========================================================================
// 4. gemm2s: bufA[j] = dinv[j] * ( relu(sc1*bufB[j]+sh1) @ W2^T )
//    (act1 folded into input read; dinv row-scaling folded into epilogue —
//     degrees are final here, unlike gemm1 which co-runs with fill)
// ===========================================================================
__global__ __launch_bounds__(256) void k_gemm2s(const float* __restrict__ in, const float* __restrict__ W,
                                                const float* __restrict__ scale, const float* __restrict__ shift,
                                                const int* __restrict__ icnt,
                                                float* __restrict__ out, int n) {
    __shared__ float4 Wl[1056];
    const float4* W4 = (const float4*)W;
    for (int i = threadIdx.x; i < 1024; i += 256) Wl[i] = W4[i];
    if (threadIdx.x < 16) {
        Wl[1024 + threadIdx.x] = ((const float4*)scale)[threadIdx.x];
        Wl[1040 + threadIdx.x] = ((const float4*)shift)[threadIdx.x];
    }
    __syncthreads();
    const float4* scl = Wl + 1024;
    const float4* shl = Wl + 1040;

    int hg = threadIdx.x >> 6;
    int h0 = hg * 16;
    int ng = threadIdx.x & 63;
    int n0 = blockIdx.x * 256 + 4 * ng;

    float acc[4][16];
#pragma unroll
    for (int j = 0; j < 4; ++j)
#pragma unroll
        for (int k = 0; k < 16; ++k) acc[j][k] = 0.0f;
    bool valid[4];
#pragma unroll
    for (int j = 0; j < 4; ++j) valid[j] = (n0 + j) < n;

    const float4* in4 = (const float4*)in;
    for (int f4 = 0; f4 < 16; ++f4) {
        float4 sc = scl[f4], sh = shl[f4];
        float4 xv[4];
#pragma unroll
        for (int j = 0; j < 4; ++j) {
            float4 v = valid[j] ? in4[(n0 + j) * 16 + f4] : float4{0.f, 0.f, 0.f, 0.f};
            v.x = fmaxf(v.x * sc.x + sh.x, 0.0f);
            v.y = fmaxf(v.y * sc.y + sh.y, 0.0f);
            v.z = fmaxf(v.z * sc.z + sh.z, 0.0f);
            v.w = fmaxf(v.w * sc.w + sh.w, 0.0f);
            xv[j] = v;
        }
#pragma unroll
        for (int hh = 0; hh < 16; ++hh) {
            float4 w = Wl[(h0 + hh) * 16 + f4];
#pragma unroll
            for (int j = 0; j < 4; ++j) {
                acc[j][hh] += xv[j].x * w.x;
                acc[j][hh] += xv[j].y * w.y;
                acc[j][hh] += xv[j].z * w.z;
                acc[j][hh] += xv[j].w * w.w;
            }
        }
    }

    // epilogue: row scale by dinv[j] = rsqrt(deg+1)
    float4* out4 = (float4*)out;
#pragma unroll
    for (int j = 0; j < 4; ++j) {
        if (!valid[j]) continue;
        float di = rsqrtf((float)(icnt[n0 + j] + 1));
#pragma unroll
        for (int q = 0; q < 4; ++q) {
            float4 o = {acc[j][4 * q] * di, acc[j][4 * q + 1] * di,
                        acc[j][4 * q + 2] * di, acc[j][4 * q + 3] * di};
            out4[(n0 + j) * 16 + (h0 >> 2) + q] = o;
        }
    }
}

// ===========================================================================
// 5. applypool: unweighted pull (g2 pre-scaled) -> act2 -> per-graph LDS
//    partials -> few global atomics.  128 nodes/block (R7-proven).
// ===========================================================================
__global__ __launch_bounds__(256) void k_applypool_f(
    const float* __restrict__ h, const int* __restrict__ icnt, const int* __restrict__ csr,
    const int* __restrict__ batch,
    const float* __restrict__ sc, const float* __restrict__ sh,
    float* gsum, float* gcnt, int n) {
    __shared__ float spart[64 * 64];
    __shared__ float scnt[64];
    int node0 = blockIdx.x * 128;
    int last = min(node0 + 127, n - 1);
    int g0 = batch[node0];
    int rc = batch[last] - g0 + 1;  // contiguous (batch sorted), <= 64
    for (int idx = threadIdx.x; idx < rc * 64; idx += 256) spart[idx] = 0.0f;
    if (threadIdx.x < rc) scnt[threadIdx.x] = 0.0f;
    __syncthreads();
    int q = threadIdx.x & 15;
    float4 s4 = ((const float4*)sc)[q];
    float4 b4 = ((const float4*)sh)[q];
    for (int it = 0; it < 8; ++it) {
        int i = node0 + it * 16 + (threadIdx.x >> 4);
        if (i < n) {
            float4 acc = pull_plain((const float4*)h, icnt, csr, i, q);
            acc.x = fmaxf(acc.x * s4.x + b4.x, 0.0f);
            acc.y = fmaxf(acc.y * s4.y + b4.y, 0.0f);
            acc.z = fmaxf(acc.z * s4.z + b4.z, 0.0f);
            acc.w = fmaxf(acc.w * s4.w + b4.w, 0.0f);
            int gl = batch[i] - g0;
            float* pp = &spart[gl * 64 + q * 4];
            atomicAdd(pp + 0, acc.x);
            atomicAdd(pp + 1, acc.y);
            atomicAdd(pp + 2, acc.z);
            atomicAdd(pp + 3, acc.w);
            if (q == 0) atomicAdd(&scnt[gl], 1.0f);
        }
    }
    __syncthreads();
    for (int idx = threadIdx.x; idx < rc * 64; idx += 256) {
        int gl = idx >> 6, f = idx & 63;
        atomicAdd(&gsum[(g0 + gl) * 64 + f], spart[idx]);
    }
    if (threadIdx.x < rc) atomicAdd(&gcnt[g0 + threadIdx.x], scnt[threadIdx.x]);
}

// ===========================================================================
// 6. MLP head
// ===========================================================================
__global__ void k_mlp(const float* __restrict__ gsum, const float* __restrict__ gcnt,
                      const float* __restrict__ l1W, const float* __restrict__ l1b,
                      const float* __restrict__ l2W, const float* __restrict__ l2b,
                      float* __restrict__ outp) {
    int g = threadIdx.x;
    if (g >= 64) return;
    float inv = 1.0f / fmaxf(gcnt[g], 1.0f);
    float p[64];
#pragma unroll
    for (int hh = 0; hh < 64; ++hh) p[hh] = gsum[g * 64 + hh] * inv;
    float o = l2b[0];
    for (int j = 0; j < 32; ++j) {
        float a = l1b[j];
#pragma unroll
        for (int hh = 0; hh < 64; ++hh) a += p[hh] * l1W[j * 64 + hh];
        o += fmaxf(a, 0.0f) * l2W[j];
    }
    outp[g] = o;
}

// ---------------------------------------------------------------------------
extern "C" void kernel_launch(void* const* d_in, const int* in_sizes, int n_in,
                              void* d_out, int out_size, void* d_ws, size_t ws_size,
                              hipStream_t stream) {
    const int N = in_sizes[0] / 64;  // 100000
    const int E = in_sizes[1] / 2;   // 1000000

    const float* x    = (const float*)d_in[0];
    const int*  row   = (const int*)d_in[1];
    const int*  colp  = ((const int*)d_in[1]) + E;
    const int*  batch = (const int*)d_in[2];
    const float* W1   = (const float*)d_in[3];
    const float* b1   = (const float*)d_in[4];
    const float* W2   = (const float*)d_in[5];
    const float* b2   = (const float*)d_in[6];
    const float* bn1g = (const float*)d_in[7];
    const float* bn1b = (const float*)d_in[8];
    const float* bn1m = (const float*)d_in[9];
    const float* bn1v = (const float*)d_in[10];
    const float* bn2g = (const float*)d_in[11];
    const float* bn2b = (const float*)d_in[12];
    const float* bn2m = (const float*)d_in[13];
    const float* bn2v = (const float*)d_in[14];
    const float* l1W  = (const float*)d_in[15];
    const float* l1b  = (const float*)d_in[16];
    const float* l2W  = (const float*)d_in[17];
    const float* l2b  = (const float*)d_in[18];
    float* out = (float*)d_out;

    // workspace layout (element offsets multiples of 4 -> 16B aligned)
    int* icnt = (int*)d_ws;                          // N+4 (icnt[N]=0 sentinel)
    float* sc1 = (float*)(icnt + N + 4);
    float* sh1 = sc1 + 64;
    float* sc2 = sh1 + 64;
    float* sh2 = sc2 + 64;
    float* gsum = sh2 + 64;                          // 4096
    float* gcnt = gsum + 4096;                       // 64
    int* csr = (int*)(gcnt + 64);                    // N*CAP
    float* bufA = (float*)(csr + (size_t)N * CAP);   // (N+1)*64 (row N = sentinel zeros)
    float* bufB = bufA + (size_t)(N + 1) * 64;       // (N+1)*64

    int nb_n    = (N + 255) / 256;
    int nb_e4   = ((E + 3) / 4 + 255) / 256;
    int nb_n16  = (N * 16 + 255) / 256;
    int nb_apl  = (N + 127) / 128;
    int nb_init = (N * (CAP / 4) + 255) / 256;

    k_init_f<<<nb_init, 256, 0, stream>>>(icnt, csr, gsum, gcnt,
                                          bufA + (size_t)N * 64, bufB + (size_t)N * 64, N,
                                          b1, bn1g, bn1b, bn1m, bn1v,
                                          b2, bn2g, bn2b, bn2m, bn2v,
                                          sc1, sh1, sc2, sh2);
    k_fillgemm_f<<<nb_n + nb_e4, 256, 0, stream>>>(nb_n, x, W1, bufA, N,
                                                   row, colp, icnt, csr, E);
    k_apply_f<<<nb_n16, 256, 0, stream>>>(bufA, icnt, csr, bufB, N);
    k_gemm2s<<<nb_n, 256, 0, stream>>>(bufB, W2, sc1, sh1, icnt, bufA, N);
    k_applypool_f<<<nb_apl, 256, 0, stream>>>(bufA, icnt, csr, batch, sc2, sh2, gsum, gcnt, N);
    k_mlp<<<1, 64, 0, stream>>>(gsum, gcnt, l1W, l1b, l2W, l2b, out);
}